// Round 1
// 9515.154 us; speedup vs baseline: 1.0733x; 1.0733x over previous
//
#include <hip/hip_runtime.h>
#include <math.h>

#define Bn 512
#define Tn 256
#define Hn 512
#define Vn 7
#define BH (Bn*Hn)          // 262144
#define NLP (Bn*Tn*Vn)      // 917504

#define NBLK 256
#define NTHR 512
#define NGRP 16             // independent batch-row groups (32 b each)
#define GBLK 16             // blocks per group (j-tiles)
#define CNT_STRIDE 32       // ints; 128B per counter line

#define KCH 64              // k per LDS chunk
#define LDW 68              // padded row stride in floats (68 % 32 == 4 -> bank spread)

// Round-9 restructure: 8x8 register tile (strided sub-tiles b=bq+4*bi, jg=jq+16*ji),
// K split 8-way across waves (kq = wave id, k-offset kq*8 per 64-k chunk).
// Halves ds_read_b128 count per FMA (LDS pipe was ~20us/step of the 40us step).
// A+W both double-buffered -> ONE barrier per chunk (9/step vs 16).
// Epilogue/logit/softmax/argmax/group-barrier expression trees kept verbatim
// (FMA summation order changes: accepted flip-reroll risk, bounded ~0.02/flip).

__device__ __forceinline__ float sigf(float x){ return 1.0f/(1.0f + expf(-x)); }

__device__ __forceinline__ void group_barrier(int* cnt, int target){
    __syncthreads();
    if (threadIdx.x == 0){
        __hip_atomic_fetch_add(cnt, 1, __ATOMIC_RELEASE, __HIP_MEMORY_SCOPE_AGENT);
        while (__hip_atomic_load(cnt, __ATOMIC_RELAXED, __HIP_MEMORY_SCOPE_AGENT) < target)
            __builtin_amdgcn_s_sleep(1);
        (void)__hip_atomic_load(cnt, __ATOMIC_ACQUIRE, __HIP_MEMORY_SCOPE_AGENT);
    }
    __syncthreads();
}

__global__ void init_kernel(float* lp, int* cnts){
    int i = blockIdx.x*blockDim.x + threadIdx.x;
    if (i < NGRP) cnts[i*CNT_STRIDE] = 0;
    for (int x = i; x < NLP; x += (int)(gridDim.x*blockDim.x)) lp[x] = 0.0f;
}

__global__ void __launch_bounds__(NTHR, 2)
decoder_rnn_kernel(const float* __restrict__ h0, const float* __restrict__ c0,
                   const float* __restrict__ tgt, const float* __restrict__ Wih,
                   const float* __restrict__ Whh, const float* __restrict__ bih,
                   const float* __restrict__ bhh, const float* __restrict__ Wout,
                   const float* __restrict__ bout, float* out, float* ws)
{
    __shared__ float W_lds[2][128*LDW];   // 69632 B (also reused as 4*64*LDW reduce buf)
    __shared__ float A_lds[2][32*LDW];    // 17408 B
    __shared__ float hn_lds[32*33];
    __shared__ int   idx_lds[32];

    float* hbuf = ws;                  // 2*BH ping-pong h
    float* cws  = ws + 2*BH;           // BH c-state
    int*   cnts = (int*)(ws + 3*BH);   // NGRP padded counters
    float* lp   = out;                 // logits -> logp in place

    const int bt = blockIdx.x & 15;    // group: all 16 j-blocks of bt share an XCD
    const int jt = blockIdx.x >> 4;
    const int b0 = bt << 5;
    const int j0 = jt << 5;

    const int tid = threadIdx.x;
    const int kq  = tid >> 6;          // wave id = K slice (k-offset kq*8 within chunk)
    const int l   = tid & 63;
    const int bq  = l >> 4;            // 0..3  : b = bq + 4*bi
    const int jq  = l & 15;            // 0..15 : jg = jq + 16*ji
    const int ar  = tid >> 4, ac = tid & 15;   // A staging: row, kquad
    int* cnt = cnts + bt*CNT_STRIDE;

    const int gtid = blockIdx.x*NTHR + threadIdx.x;
    const int nthr = NBLK*NTHR;

    // ---- per-block state init (verbatim) ----
    #pragma unroll
    for (int i = 0; i < 8; ++i){
        const int f = threadIdx.x + (i << 9);
        const int r = f >> 7, c4 = f & 127;
        *(float4*)(hbuf + (long)(b0 + r)*Hn + (c4 << 2)) =
            *(const float4*)(h0 + (long)(b0 + r)*Hn + (c4 << 2));
    }
    if (threadIdx.x < 256){
        const int r = threadIdx.x >> 3, c4 = threadIdx.x & 7;
        *(float4*)(cws + (long)(b0 + r)*Hn + j0 + (c4 << 2)) =
            *(const float4*)(c0 + (long)(b0 + r)*Hn + j0 + (c4 << 2));
    }
    __syncthreads();

    for (int t = 0; t < Tn; ++t){
        const float* hprev = hbuf + (t & 1)*BH;
        float*       hnext = hbuf + ((t + 1) & 1)*BH;

        // ---- argmax -> one-hot index (frozen) ----
        if (tid < 32){
            const int  bl = tid;
            const long b  = b0 + bl;
            float best; int am = 0;
            if (t == 0){
                const float* xp = tgt + (b*Tn)*Vn;
                best = xp[0];
                #pragma unroll
                for (int v = 1; v < Vn; ++v){ float xv = xp[v]; if (xv > best){ best = xv; am = v; } }
            } else {
                const float* xp = lp + (b*Tn + (t-1))*Vn;
                best = xp[0] + bout[0];
                #pragma unroll
                for (int v = 1; v < Vn; ++v){ float xv = xp[v] + bout[v]; if (xv > best){ best = xv; am = v; } }
            }
            idx_lds[bl] = am;
        }

        float acc[8][8];
        #pragma unroll
        for (int a = 0; a < 8; ++a)
            #pragma unroll
            for (int g = 0; g < 8; ++g) acc[a][g] = 0.0f;

        float4 wreg[4], areg;
        // ---- prologue: stage chunk 0 ----
        {
            #pragma unroll
            for (int i = 0; i < 4; ++i){
                const int f = tid + (i << 9);
                const int r = f >> 4, c4 = f & 15;
                wreg[i] = *(const float4*)(Whh + (long)(((r>>5)<<9) + j0 + (r&31))*Hn + (c4 << 2));
            }
            areg = *(const float4*)(hprev + (long)(b0 + ar)*Hn + (ac << 2));
            #pragma unroll
            for (int i = 0; i < 4; ++i){
                const int f = tid + (i << 9);
                const int r = f >> 4, c4 = f & 15;
                *(float4*)(&W_lds[0][r*LDW + (c4 << 2)]) = wreg[i];
            }
            *(float4*)(&A_lds[0][ar*LDW + (ac << 2)]) = areg;
        }
        __syncthreads();

        for (int c = 0; c < 8; ++c){
            // issue next-chunk global loads early (hidden under the 512-FMA compute)
            if (c < 7){
                const int cb = (c + 1) << 6;
                #pragma unroll
                for (int i = 0; i < 4; ++i){
                    const int f = tid + (i << 9);
                    const int r = f >> 4, c4 = f & 15;
                    wreg[i] = *(const float4*)(Whh + (long)(((r>>5)<<9) + j0 + (r&31))*Hn + cb + (c4 << 2));
                }
                areg = *(const float4*)(hprev + (long)(b0 + ar)*Hn + cb + (ac << 2));
            }
            // ---- compute chunk c : 8x8 strided tile, 2 k-quads ----
            {
                const float* Ab = &A_lds[c & 1][bq*LDW + (kq << 3)];
                const float* Wb = &W_lds[c & 1][jq*LDW + (kq << 3)];
                #pragma unroll
                for (int q = 0; q < 2; ++q){
                    float4 av[8], wv[8];
                    #pragma unroll
                    for (int i = 0; i < 8; ++i)
                        av[i] = *(const float4*)(Ab + i*(4*LDW) + (q << 2));
                    #pragma unroll
                    for (int i = 0; i < 8; ++i)
                        wv[i] = *(const float4*)(Wb + i*(16*LDW) + (q << 2));
                    #pragma unroll
                    for (int bi = 0; bi < 8; ++bi)
                        #pragma unroll
                        for (int ji = 0; ji < 8; ++ji){
                            float s = acc[bi][ji];
                            s = fmaf(av[bi].x, wv[ji].x, s);
                            s = fmaf(av[bi].y, wv[ji].y, s);
                            s = fmaf(av[bi].z, wv[ji].z, s);
                            s = fmaf(av[bi].w, wv[ji].w, s);
                            acc[bi][ji] = s;
                        }
                }
            }
            // write next chunk into the other buffer (no extra barrier needed)
            if (c < 7){
                const int nb = (c + 1) & 1;
                #pragma unroll
                for (int i = 0; i < 4; ++i){
                    const int f = tid + (i << 9);
                    const int r = f >> 4, c4 = f & 15;
                    *(float4*)(&W_lds[nb][r*LDW + (c4 << 2)]) = wreg[i];
                }
                *(float4*)(&A_lds[nb][ar*LDW + (ac << 2)]) = areg;
            }
            __syncthreads();
        }

        // ---- K-combine: fold 8 wave-slices -> 4, park in red (reuses W_lds) ----
        float* red = &W_lds[0][0];     // 4*64*LDW = 17408 floats = exactly W_lds
        if (kq >= 4){
            float* p = red + ((kq - 4)*64 + l)*LDW;
            #pragma unroll
            for (int bi = 0; bi < 8; ++bi){
                *(float4*)(p + (bi << 3))     = make_float4(acc[bi][0], acc[bi][1], acc[bi][2], acc[bi][3]);
                *(float4*)(p + (bi << 3) + 4) = make_float4(acc[bi][4], acc[bi][5], acc[bi][6], acc[bi][7]);
            }
        }
        __syncthreads();
        if (kq < 4){
            float* p = red + (kq*64 + l)*LDW;
            #pragma unroll
            for (int bi = 0; bi < 8; ++bi){
                float4 r0 = *(const float4*)(p + (bi << 3));
                float4 r1 = *(const float4*)(p + (bi << 3) + 4);
                acc[bi][0] += r0.x; acc[bi][1] += r0.y; acc[bi][2] += r0.z; acc[bi][3] += r0.w;
                acc[bi][4] += r1.x; acc[bi][5] += r1.y; acc[bi][6] += r1.z; acc[bi][7] += r1.w;
            }
            #pragma unroll
            for (int bi = 0; bi < 8; ++bi){
                *(float4*)(p + (bi << 3))     = make_float4(acc[bi][0], acc[bi][1], acc[bi][2], acc[bi][3]);
                *(float4*)(p + (bi << 3) + 4) = make_float4(acc[bi][4], acc[bi][5], acc[bi][6], acc[bi][7]);
            }
        }
        __syncthreads();

        // ---- epilogue: all 512 threads, 2 cells each (expressions frozen) ----
        {
            const int b  = tid >> 4;           // 0..31
            const int jp = tid & 15;
            const int ix = idx_lds[b];
            #pragma unroll
            for (int u = 0; u < 2; ++u){
                const int j  = (jp << 1) + u;                     // 0..31
                const int lo = ((b & 3) << 4) + (j & 15);         // owner lane
                const int vb = ((b >> 2) << 3) + (j >> 4);        // bi*8 + (j>>4)
                float g4[4];
                #pragma unroll
                for (int g = 0; g < 4; ++g){
                    const int v = vb + (g << 1);                  // + ji gate part
                    float s  = red[(      lo)*LDW + v];
                    s       += red[( 64 + lo)*LDW + v];
                    s       += red[(128 + lo)*LDW + v];
                    s       += red[(192 + lo)*LDW + v];
                    const int r = (g << 9) + j0 + j;
                    g4[g] = s + (Wih[r*Vn + ix] + bih[r] + bhh[r]);
                }
                const long bg = b0 + b;
                const int  jj = j0 + j;
                const float iv = sigf(g4[0]);
                const float fv = sigf(g4[1]);
                const float gv = tanhf(g4[2]);
                const float ov = sigf(g4[3]);
                const float cold = cws[bg*Hn + jj];
                const float cn = fv*cold + iv*gv;
                cws[bg*Hn + jj] = cn;
                const float hn = ov * tanhf(cn);
                hnext[bg*Hn + jj] = hn;
                hn_lds[b*33 + j] = hn;
            }
        }
        __syncthreads();

        // ---- partial logits (frozen) ----
        if (tid < 224){
            const int bl = tid / 7;
            const int v  = tid % 7;
            const float* wo = Wout + v*Hn + j0;
            float s = 0.0f;
            #pragma unroll
            for (int jj = 0; jj < 32; ++jj)
                s = fmaf(hn_lds[bl*33 + jj], wo[jj], s);
            atomicAdd(&lp[((long)(b0 + bl)*Tn + t)*Vn + v], s);
        }

        group_barrier(cnt, GBLK*(t+1));
    }

    // ---- final: hT, cT, in-place log_softmax (frozen) ----
    for (int i = gtid; i < BH; i += nthr){
        out[NLP + i]      = hbuf[i];   // T=256 even -> final h in buffer 0
        out[NLP + BH + i] = cws[i];
    }
    {
        const long row = gtid;         // exactly B*T rows
        float x[Vn]; float m = -INFINITY;
        #pragma unroll
        for (int v = 0; v < Vn; ++v){ x[v] = lp[row*Vn + v] + bout[v]; m = fmaxf(m, x[v]); }
        float s = 0.0f;
        #pragma unroll
        for (int v = 0; v < Vn; ++v) s += expf(x[v] - m);
        const float ls = logf(s);
        #pragma unroll
        for (int v = 0; v < Vn; ++v) lp[row*Vn + v] = x[v] - m - ls;
    }
}

extern "C" void kernel_launch(void* const* d_in, const int* in_sizes, int n_in,
                              void* d_out, int out_size, void* d_ws, size_t ws_size,
                              hipStream_t stream) {
    const float* h0   = (const float*)d_in[0];
    const float* c0   = (const float*)d_in[1];
    const float* tgt  = (const float*)d_in[2];
    const float* Wih  = (const float*)d_in[3];
    const float* Whh  = (const float*)d_in[4];
    const float* bih  = (const float*)d_in[5];
    const float* bhh  = (const float*)d_in[6];
    const float* Wout = (const float*)d_in[7];
    const float* bout = (const float*)d_in[8];
    float* out = (float*)d_out;
    float* ws  = (float*)d_ws;               // 3*BH floats + counters
    int*   cnts = (int*)(ws + 3*BH);

    init_kernel<<<256, 256, 0, stream>>>(out, cnts);

    void* args[] = { &h0, &c0, &tgt, &Wih, &Whh, &bih, &bhh, &Wout, &bout, &out, &ws };
    (void)hipLaunchCooperativeKernel((const void*)decoder_rnn_kernel,
                               dim3(NBLK), dim3(NTHR), args, 0, stream);
}

// Round 2
// 7521.378 us; speedup vs baseline: 1.3579x; 1.2651x over previous
//
#include <hip/hip_runtime.h>
#include <math.h>

#define Bn 512
#define Tn 256
#define Hn 512
#define Vn 7
#define BH (Bn*Hn)          // 262144
#define NLP (Bn*Tn*Vn)      // 917504

#define NBLK 256
#define NTHR 512
#define NGRP 16             // independent batch-row groups (32 b each)
#define GBLK 16             // blocks per group (j-tiles)
#define CNT_STRIDE 32       // ints; 128B per counter line

#define KCH 64              // k per LDS chunk
#define LDW 68              // padded row stride in floats (68 % 32 == 4 -> bank spread)

// Round-10: I$-footprint fix. Round 0->1 showed T = LDS_term + ~36.6us FIXED;
// VALU issue is only ~10.5us/step -> the fixed cost is not data-side. The fully
// unrolled 8-chunk GEMM made the step body ~45-50KB, re-walked cold through the
// 32KB L1 I$ every one of 256 steps. Chunk loop is now #pragma unroll 1 with
// runtime-indexed dbuf + branchless clamped prefetch (last iter re-loads chunk 7
// and rewrites identical bytes into the live buffer - benign same-value race).
// FMA order and all epilogue/logit/softmax/argmax expression trees are verbatim
// round 1 (absmax expected unchanged at ~0.043).

__device__ __forceinline__ float sigf(float x){ return 1.0f/(1.0f + expf(-x)); }

__device__ __forceinline__ void group_barrier(int* cnt, int target){
    __syncthreads();
    if (threadIdx.x == 0){
        __hip_atomic_fetch_add(cnt, 1, __ATOMIC_RELEASE, __HIP_MEMORY_SCOPE_AGENT);
        while (__hip_atomic_load(cnt, __ATOMIC_RELAXED, __HIP_MEMORY_SCOPE_AGENT) < target)
            __builtin_amdgcn_s_sleep(1);
        (void)__hip_atomic_load(cnt, __ATOMIC_ACQUIRE, __HIP_MEMORY_SCOPE_AGENT);
    }
    __syncthreads();
}

__global__ void init_kernel(float* lp, int* cnts){
    int i = blockIdx.x*blockDim.x + threadIdx.x;
    if (i < NGRP) cnts[i*CNT_STRIDE] = 0;
    for (int x = i; x < NLP; x += (int)(gridDim.x*blockDim.x)) lp[x] = 0.0f;
}

__global__ void __launch_bounds__(NTHR, 2)
decoder_rnn_kernel(const float* __restrict__ h0, const float* __restrict__ c0,
                   const float* __restrict__ tgt, const float* __restrict__ Wih,
                   const float* __restrict__ Whh, const float* __restrict__ bih,
                   const float* __restrict__ bhh, const float* __restrict__ Wout,
                   const float* __restrict__ bout, float* out, float* ws)
{
    __shared__ float W_lds[2][128*LDW];   // 69632 B (also reused as 4*64*LDW reduce buf)
    __shared__ float A_lds[2][32*LDW];    // 17408 B
    __shared__ float hn_lds[32*33];
    __shared__ int   idx_lds[32];

    float* hbuf = ws;                  // 2*BH ping-pong h
    float* cws  = ws + 2*BH;           // BH c-state
    int*   cnts = (int*)(ws + 3*BH);   // NGRP padded counters
    float* lp   = out;                 // logits -> logp in place

    const int bt = blockIdx.x & 15;    // group: all 16 j-blocks of bt share an XCD
    const int jt = blockIdx.x >> 4;
    const int b0 = bt << 5;
    const int j0 = jt << 5;

    const int tid = threadIdx.x;
    const int kq  = tid >> 6;          // wave id = K slice (k-offset kq*8 within chunk)
    const int l   = tid & 63;
    const int bq  = l >> 4;            // 0..3  : b = bq + 4*bi
    const int jq  = l & 15;            // 0..15 : jg = jq + 16*ji
    const int ar  = tid >> 4, ac = tid & 15;   // A staging: row, kquad
    int* cnt = cnts + bt*CNT_STRIDE;

    const int gtid = blockIdx.x*NTHR + threadIdx.x;
    const int nthr = NBLK*NTHR;

    // ---- t-invariant staging offsets (hoisted out of the step loop) ----
    int wgoff[4], wloff[4];
    #pragma unroll
    for (int i = 0; i < 4; ++i){
        const int f = tid + (i << 9);
        const int r = f >> 4, c4 = f & 15;
        wgoff[i] = (((r>>5)<<9) + j0 + (r&31))*Hn + (c4 << 2);
        wloff[i] = r*LDW + (c4 << 2);
    }
    const int agoff = (b0 + ar)*Hn + (ac << 2);
    const int aloff = ar*LDW + (ac << 2);
    const int aroff = bq*LDW + (kq << 3);     // compute-phase A base
    const int wroff = jq*LDW + (kq << 3);     // compute-phase W base

    // ---- per-block state init (verbatim) ----
    #pragma unroll
    for (int i = 0; i < 8; ++i){
        const int f = threadIdx.x + (i << 9);
        const int r = f >> 7, c4 = f & 127;
        *(float4*)(hbuf + (long)(b0 + r)*Hn + (c4 << 2)) =
            *(const float4*)(h0 + (long)(b0 + r)*Hn + (c4 << 2));
    }
    if (threadIdx.x < 256){
        const int r = threadIdx.x >> 3, c4 = threadIdx.x & 7;
        *(float4*)(cws + (long)(b0 + r)*Hn + j0 + (c4 << 2)) =
            *(const float4*)(c0 + (long)(b0 + r)*Hn + j0 + (c4 << 2));
    }
    __syncthreads();

    for (int t = 0; t < Tn; ++t){
        const float* hprev = hbuf + (t & 1)*BH;
        float*       hnext = hbuf + ((t + 1) & 1)*BH;

        // ---- argmax -> one-hot index (frozen) ----
        if (tid < 32){
            const int  bl = tid;
            const long b  = b0 + bl;
            float best; int am = 0;
            if (t == 0){
                const float* xp = tgt + (b*Tn)*Vn;
                best = xp[0];
                #pragma unroll
                for (int v = 1; v < Vn; ++v){ float xv = xp[v]; if (xv > best){ best = xv; am = v; } }
            } else {
                const float* xp = lp + (b*Tn + (t-1))*Vn;
                best = xp[0] + bout[0];
                #pragma unroll
                for (int v = 1; v < Vn; ++v){ float xv = xp[v] + bout[v]; if (xv > best){ best = xv; am = v; } }
            }
            idx_lds[bl] = am;
        }

        float acc[8][8];
        #pragma unroll
        for (int a = 0; a < 8; ++a)
            #pragma unroll
            for (int g = 0; g < 8; ++g) acc[a][g] = 0.0f;

        float4 wreg[4], areg;
        // ---- prologue: stage chunk 0 into buf 0 ----
        {
            #pragma unroll
            for (int i = 0; i < 4; ++i)
                wreg[i] = *(const float4*)(Whh + wgoff[i]);
            areg = *(const float4*)(hprev + agoff);
            #pragma unroll
            for (int i = 0; i < 4; ++i)
                *(float4*)(&W_lds[0][wloff[i]]) = wreg[i];
            *(float4*)(&A_lds[0][aloff]) = areg;
        }
        __syncthreads();

        // ---- GEMM: rolled chunk loop (I$-resident body) ----
        #pragma unroll 1
        for (int c = 0; c < 8; ++c){
            const int cn = (c < 7) ? (c + 1) : 7;   // branchless clamp
            const int cb = cn << 6;
            // issue next-chunk global loads early (hidden under the 512-FMA compute)
            #pragma unroll
            for (int i = 0; i < 4; ++i)
                wreg[i] = *(const float4*)(Whh + wgoff[i] + cb);
            areg = *(const float4*)(hprev + agoff + cb);
            // ---- compute chunk c : 8x8 strided tile, 2 k-quads ----
            {
                const float* Ab = &A_lds[c & 1][aroff];
                const float* Wb = &W_lds[c & 1][wroff];
                #pragma unroll
                for (int q = 0; q < 2; ++q){
                    float4 av[8], wv[8];
                    #pragma unroll
                    for (int i = 0; i < 8; ++i)
                        av[i] = *(const float4*)(Ab + i*(4*LDW) + (q << 2));
                    #pragma unroll
                    for (int i = 0; i < 8; ++i)
                        wv[i] = *(const float4*)(Wb + i*(16*LDW) + (q << 2));
                    #pragma unroll
                    for (int bi = 0; bi < 8; ++bi)
                        #pragma unroll
                        for (int ji = 0; ji < 8; ++ji){
                            float s = acc[bi][ji];
                            s = fmaf(av[bi].x, wv[ji].x, s);
                            s = fmaf(av[bi].y, wv[ji].y, s);
                            s = fmaf(av[bi].z, wv[ji].z, s);
                            s = fmaf(av[bi].w, wv[ji].w, s);
                            acc[bi][ji] = s;
                        }
                }
            }
            // write chunk cn into buf[cn&1]; at c==7 this rewrites identical
            // bytes into the live buffer (same-value race, benign)
            {
                const int nb = cn & 1;
                #pragma unroll
                for (int i = 0; i < 4; ++i)
                    *(float4*)(&W_lds[nb][wloff[i]]) = wreg[i];
                *(float4*)(&A_lds[nb][aloff]) = areg;
            }
            __syncthreads();
        }

        // ---- K-combine: fold 8 wave-slices -> 4, park in red (reuses W_lds) ----
        float* red = &W_lds[0][0];     // 4*64*LDW = 17408 floats = exactly W_lds
        if (kq >= 4){
            float* p = red + ((kq - 4)*64 + l)*LDW;
            #pragma unroll
            for (int bi = 0; bi < 8; ++bi){
                *(float4*)(p + (bi << 3))     = make_float4(acc[bi][0], acc[bi][1], acc[bi][2], acc[bi][3]);
                *(float4*)(p + (bi << 3) + 4) = make_float4(acc[bi][4], acc[bi][5], acc[bi][6], acc[bi][7]);
            }
        }
        __syncthreads();
        if (kq < 4){
            float* p = red + (kq*64 + l)*LDW;
            #pragma unroll
            for (int bi = 0; bi < 8; ++bi){
                float4 r0 = *(const float4*)(p + (bi << 3));
                float4 r1 = *(const float4*)(p + (bi << 3) + 4);
                acc[bi][0] += r0.x; acc[bi][1] += r0.y; acc[bi][2] += r0.z; acc[bi][3] += r0.w;
                acc[bi][4] += r1.x; acc[bi][5] += r1.y; acc[bi][6] += r1.z; acc[bi][7] += r1.w;
            }
            #pragma unroll
            for (int bi = 0; bi < 8; ++bi){
                *(float4*)(p + (bi << 3))     = make_float4(acc[bi][0], acc[bi][1], acc[bi][2], acc[bi][3]);
                *(float4*)(p + (bi << 3) + 4) = make_float4(acc[bi][4], acc[bi][5], acc[bi][6], acc[bi][7]);
            }
        }
        __syncthreads();

        // ---- epilogue: all 512 threads, 2 cells each (expressions frozen) ----
        {
            const int b  = tid >> 4;           // 0..31
            const int jp = tid & 15;
            const int ix = idx_lds[b];
            #pragma unroll
            for (int u = 0; u < 2; ++u){
                const int j  = (jp << 1) + u;                     // 0..31
                const int lo = ((b & 3) << 4) + (j & 15);         // owner lane
                const int vb = ((b >> 2) << 3) + (j >> 4);        // bi*8 + (j>>4)
                float g4[4];
                #pragma unroll
                for (int g = 0; g < 4; ++g){
                    const int v = vb + (g << 1);                  // + ji gate part
                    float s  = red[(      lo)*LDW + v];
                    s       += red[( 64 + lo)*LDW + v];
                    s       += red[(128 + lo)*LDW + v];
                    s       += red[(192 + lo)*LDW + v];
                    const int r = (g << 9) + j0 + j;
                    g4[g] = s + (Wih[r*Vn + ix] + bih[r] + bhh[r]);
                }
                const long bg = b0 + b;
                const int  jj = j0 + j;
                const float iv = sigf(g4[0]);
                const float fv = sigf(g4[1]);
                const float gv = tanhf(g4[2]);
                const float ov = sigf(g4[3]);
                const float cold = cws[bg*Hn + jj];
                const float cn2 = fv*cold + iv*gv;
                cws[bg*Hn + jj] = cn2;
                const float hn = ov * tanhf(cn2);
                hnext[bg*Hn + jj] = hn;
                hn_lds[b*33 + j] = hn;
            }
        }
        __syncthreads();

        // ---- partial logits (frozen) ----
        if (tid < 224){
            const int bl = tid / 7;
            const int v  = tid % 7;
            const float* wo = Wout + v*Hn + j0;
            float s = 0.0f;
            #pragma unroll
            for (int jj = 0; jj < 32; ++jj)
                s = fmaf(hn_lds[bl*33 + jj], wo[jj], s);
            atomicAdd(&lp[((long)(b0 + bl)*Tn + t)*Vn + v], s);
        }

        group_barrier(cnt, GBLK*(t+1));
    }

    // ---- final: hT, cT, in-place log_softmax (frozen) ----
    for (int i = gtid; i < BH; i += nthr){
        out[NLP + i]      = hbuf[i];   // T=256 even -> final h in buffer 0
        out[NLP + BH + i] = cws[i];
    }
    {
        const long row = gtid;         // exactly B*T rows
        float x[Vn]; float m = -INFINITY;
        #pragma unroll
        for (int v = 0; v < Vn; ++v){ x[v] = lp[row*Vn + v] + bout[v]; m = fmaxf(m, x[v]); }
        float s = 0.0f;
        #pragma unroll
        for (int v = 0; v < Vn; ++v) s += expf(x[v] - m);
        const float ls = logf(s);
        #pragma unroll
        for (int v = 0; v < Vn; ++v) lp[row*Vn + v] = x[v] - m - ls;
    }
}

extern "C" void kernel_launch(void* const* d_in, const int* in_sizes, int n_in,
                              void* d_out, int out_size, void* d_ws, size_t ws_size,
                              hipStream_t stream) {
    const float* h0   = (const float*)d_in[0];
    const float* c0   = (const float*)d_in[1];
    const float* tgt  = (const float*)d_in[2];
    const float* Wih  = (const float*)d_in[3];
    const float* Whh  = (const float*)d_in[4];
    const float* bih  = (const float*)d_in[5];
    const float* bhh  = (const float*)d_in[6];
    const float* Wout = (const float*)d_in[7];
    const float* bout = (const float*)d_in[8];
    float* out = (float*)d_out;
    float* ws  = (float*)d_ws;               // 3*BH floats + counters
    int*   cnts = (int*)(ws + 3*BH);

    init_kernel<<<256, 256, 0, stream>>>(out, cnts);

    void* args[] = { &h0, &c0, &tgt, &Wih, &Whh, &bih, &bhh, &Wout, &bout, &out, &ws };
    (void)hipLaunchCooperativeKernel((const void*)decoder_rnn_kernel,
                               dim3(NBLK), dim3(NTHR), args, 0, stream);
}

// Round 3
// 7435.056 us; speedup vs baseline: 1.3736x; 1.0116x over previous
//
#include <hip/hip_runtime.h>
#include <math.h>

#define Bn 512
#define Tn 256
#define Hn 512
#define Vn 7
#define BH (Bn*Hn)          // 262144
#define NLP (Bn*Tn*Vn)      // 917504

#define NBLK 256
#define NTHR 512
#define NGRP 16             // independent batch-row groups (32 b each)
#define GBLK 16             // blocks per group (j-tiles)
#define CNT_STRIDE 32       // ints; 128B per counter line

#define KCH 64              // k per LDS chunk
#define LDW 68              // padded row stride in floats (68 % 32 == 4 -> bank spread)

// Round-11: phase-overlap fix. R2 showed step time ~= SUM of phase costs
// (reads 8-10us + FMA 10.3us + writes + barriers + tail) because all 8 waves
// leave each barrier together and alternate read-burst / FMA-burst in lockstep
// (LDS pipe and VALU never overlap). Fix: load the ENTIRE chunk's fragments
// upfront into registers (av0/wv0/av1/wv1 = 32 float4 = 128 VGPR; budget is
// 256/wave at 2 waves/SIMD, we were only at 128). The wave issues all 32
// ds_read_b128 back-to-back and the compiler's fine-grained lgkmcnt lets FMAs
// overlap the read stream. FMA issue ORDER is byte-identical to R2 (same
// bi/ji/xyzw sequence) -> absmax should stay in the 0.015-0.043 band.
// Everything outside the chunk body is frozen from R2.

__device__ __forceinline__ float sigf(float x){ return 1.0f/(1.0f + expf(-x)); }

__device__ __forceinline__ void group_barrier(int* cnt, int target){
    __syncthreads();
    if (threadIdx.x == 0){
        __hip_atomic_fetch_add(cnt, 1, __ATOMIC_RELEASE, __HIP_MEMORY_SCOPE_AGENT);
        while (__hip_atomic_load(cnt, __ATOMIC_RELAXED, __HIP_MEMORY_SCOPE_AGENT) < target)
            __builtin_amdgcn_s_sleep(1);
        (void)__hip_atomic_load(cnt, __ATOMIC_ACQUIRE, __HIP_MEMORY_SCOPE_AGENT);
    }
    __syncthreads();
}

__global__ void init_kernel(float* lp, int* cnts){
    int i = blockIdx.x*blockDim.x + threadIdx.x;
    if (i < NGRP) cnts[i*CNT_STRIDE] = 0;
    for (int x = i; x < NLP; x += (int)(gridDim.x*blockDim.x)) lp[x] = 0.0f;
}

__global__ void __launch_bounds__(NTHR, 2)
decoder_rnn_kernel(const float* __restrict__ h0, const float* __restrict__ c0,
                   const float* __restrict__ tgt, const float* __restrict__ Wih,
                   const float* __restrict__ Whh, const float* __restrict__ bih,
                   const float* __restrict__ bhh, const float* __restrict__ Wout,
                   const float* __restrict__ bout, float* out, float* ws)
{
    __shared__ float W_lds[2][128*LDW];   // 69632 B (also reused as 4*64*LDW reduce buf)
    __shared__ float A_lds[2][32*LDW];    // 17408 B
    __shared__ float hn_lds[32*33];
    __shared__ int   idx_lds[32];

    float* hbuf = ws;                  // 2*BH ping-pong h
    float* cws  = ws + 2*BH;           // BH c-state
    int*   cnts = (int*)(ws + 3*BH);   // NGRP padded counters
    float* lp   = out;                 // logits -> logp in place

    const int bt = blockIdx.x & 15;    // group: all 16 j-blocks of bt share an XCD
    const int jt = blockIdx.x >> 4;
    const int b0 = bt << 5;
    const int j0 = jt << 5;

    const int tid = threadIdx.x;
    const int kq  = tid >> 6;          // wave id = K slice (k-offset kq*8 within chunk)
    const int l   = tid & 63;
    const int bq  = l >> 4;            // 0..3  : b = bq + 4*bi
    const int jq  = l & 15;            // 0..15 : jg = jq + 16*ji
    const int ar  = tid >> 4, ac = tid & 15;   // A staging: row, kquad
    int* cnt = cnts + bt*CNT_STRIDE;

    const int gtid = blockIdx.x*NTHR + threadIdx.x;
    const int nthr = NBLK*NTHR;

    // ---- t-invariant staging offsets (hoisted out of the step loop) ----
    int wgoff[4], wloff[4];
    #pragma unroll
    for (int i = 0; i < 4; ++i){
        const int f = tid + (i << 9);
        const int r = f >> 4, c4 = f & 15;
        wgoff[i] = (((r>>5)<<9) + j0 + (r&31))*Hn + (c4 << 2);
        wloff[i] = r*LDW + (c4 << 2);
    }
    const int agoff = (b0 + ar)*Hn + (ac << 2);
    const int aloff = ar*LDW + (ac << 2);
    const int aroff = bq*LDW + (kq << 3);     // compute-phase A base
    const int wroff = jq*LDW + (kq << 3);     // compute-phase W base
    const int lg_bl = tid / 7;                // logits-phase indices (hoisted)
    const int lg_v  = tid % 7;

    // ---- per-block state init (verbatim) ----
    #pragma unroll
    for (int i = 0; i < 8; ++i){
        const int f = threadIdx.x + (i << 9);
        const int r = f >> 7, c4 = f & 127;
        *(float4*)(hbuf + (long)(b0 + r)*Hn + (c4 << 2)) =
            *(const float4*)(h0 + (long)(b0 + r)*Hn + (c4 << 2));
    }
    if (threadIdx.x < 256){
        const int r = threadIdx.x >> 3, c4 = threadIdx.x & 7;
        *(float4*)(cws + (long)(b0 + r)*Hn + j0 + (c4 << 2)) =
            *(const float4*)(c0 + (long)(b0 + r)*Hn + j0 + (c4 << 2));
    }
    __syncthreads();

    for (int t = 0; t < Tn; ++t){
        const float* hprev = hbuf + (t & 1)*BH;
        float*       hnext = hbuf + ((t + 1) & 1)*BH;

        // ---- argmax -> one-hot index (frozen) ----
        if (tid < 32){
            const int  bl = tid;
            const long b  = b0 + bl;
            float best; int am = 0;
            if (t == 0){
                const float* xp = tgt + (b*Tn)*Vn;
                best = xp[0];
                #pragma unroll
                for (int v = 1; v < Vn; ++v){ float xv = xp[v]; if (xv > best){ best = xv; am = v; } }
            } else {
                const float* xp = lp + (b*Tn + (t-1))*Vn;
                best = xp[0] + bout[0];
                #pragma unroll
                for (int v = 1; v < Vn; ++v){ float xv = xp[v] + bout[v]; if (xv > best){ best = xv; am = v; } }
            }
            idx_lds[bl] = am;
        }

        float acc[8][8];
        #pragma unroll
        for (int a = 0; a < 8; ++a)
            #pragma unroll
            for (int g = 0; g < 8; ++g) acc[a][g] = 0.0f;

        float4 wreg[4], areg;
        // ---- prologue: stage chunk 0 into buf 0 ----
        {
            #pragma unroll
            for (int i = 0; i < 4; ++i)
                wreg[i] = *(const float4*)(Whh + wgoff[i]);
            areg = *(const float4*)(hprev + agoff);
            #pragma unroll
            for (int i = 0; i < 4; ++i)
                *(float4*)(&W_lds[0][wloff[i]]) = wreg[i];
            *(float4*)(&A_lds[0][aloff]) = areg;
        }
        __syncthreads();

        // ---- GEMM: rolled chunk loop (I$-resident body) ----
        #pragma unroll 1
        for (int c = 0; c < 8; ++c){
            const int cn = (c < 7) ? (c + 1) : 7;   // branchless clamp
            const int cb = cn << 6;
            // issue next-chunk global loads early (hidden under the FMA block)
            #pragma unroll
            for (int i = 0; i < 4; ++i)
                wreg[i] = *(const float4*)(Whh + wgoff[i] + cb);
            areg = *(const float4*)(hprev + agoff + cb);

            // ---- compute chunk c : load ALL fragments upfront (32 b128 ->
            //      128 VGPR), then the two FMA blocks in the frozen order ----
            {
                const float* Ab = &A_lds[c & 1][aroff];
                const float* Wb = &W_lds[c & 1][wroff];
                float4 av0[8], wv0[8], av1[8], wv1[8];
                #pragma unroll
                for (int i = 0; i < 8; ++i)
                    av0[i] = *(const float4*)(Ab + i*(4*LDW));
                #pragma unroll
                for (int i = 0; i < 8; ++i)
                    wv0[i] = *(const float4*)(Wb + i*(16*LDW));
                #pragma unroll
                for (int i = 0; i < 8; ++i)
                    av1[i] = *(const float4*)(Ab + i*(4*LDW) + 4);
                #pragma unroll
                for (int i = 0; i < 8; ++i)
                    wv1[i] = *(const float4*)(Wb + i*(16*LDW) + 4);
                #pragma unroll
                for (int bi = 0; bi < 8; ++bi)
                    #pragma unroll
                    for (int ji = 0; ji < 8; ++ji){
                        float s = acc[bi][ji];
                        s = fmaf(av0[bi].x, wv0[ji].x, s);
                        s = fmaf(av0[bi].y, wv0[ji].y, s);
                        s = fmaf(av0[bi].z, wv0[ji].z, s);
                        s = fmaf(av0[bi].w, wv0[ji].w, s);
                        acc[bi][ji] = s;
                    }
                #pragma unroll
                for (int bi = 0; bi < 8; ++bi)
                    #pragma unroll
                    for (int ji = 0; ji < 8; ++ji){
                        float s = acc[bi][ji];
                        s = fmaf(av1[bi].x, wv1[ji].x, s);
                        s = fmaf(av1[bi].y, wv1[ji].y, s);
                        s = fmaf(av1[bi].z, wv1[ji].z, s);
                        s = fmaf(av1[bi].w, wv1[ji].w, s);
                        acc[bi][ji] = s;
                    }
            }
            // write chunk cn into buf[cn&1]; at c==7 this rewrites identical
            // bytes into the live buffer (same-value race, benign)
            {
                const int nb = cn & 1;
                #pragma unroll
                for (int i = 0; i < 4; ++i)
                    *(float4*)(&W_lds[nb][wloff[i]]) = wreg[i];
                *(float4*)(&A_lds[nb][aloff]) = areg;
            }
            __syncthreads();
        }

        // ---- K-combine: fold 8 wave-slices -> 4, park in red (reuses W_lds) ----
        float* red = &W_lds[0][0];     // 4*64*LDW = 17408 floats = exactly W_lds
        if (kq >= 4){
            float* p = red + ((kq - 4)*64 + l)*LDW;
            #pragma unroll
            for (int bi = 0; bi < 8; ++bi){
                *(float4*)(p + (bi << 3))     = make_float4(acc[bi][0], acc[bi][1], acc[bi][2], acc[bi][3]);
                *(float4*)(p + (bi << 3) + 4) = make_float4(acc[bi][4], acc[bi][5], acc[bi][6], acc[bi][7]);
            }
        }
        __syncthreads();
        if (kq < 4){
            float* p = red + (kq*64 + l)*LDW;
            #pragma unroll
            for (int bi = 0; bi < 8; ++bi){
                float4 r0 = *(const float4*)(p + (bi << 3));
                float4 r1 = *(const float4*)(p + (bi << 3) + 4);
                acc[bi][0] += r0.x; acc[bi][1] += r0.y; acc[bi][2] += r0.z; acc[bi][3] += r0.w;
                acc[bi][4] += r1.x; acc[bi][5] += r1.y; acc[bi][6] += r1.z; acc[bi][7] += r1.w;
            }
            #pragma unroll
            for (int bi = 0; bi < 8; ++bi){
                *(float4*)(p + (bi << 3))     = make_float4(acc[bi][0], acc[bi][1], acc[bi][2], acc[bi][3]);
                *(float4*)(p + (bi << 3) + 4) = make_float4(acc[bi][4], acc[bi][5], acc[bi][6], acc[bi][7]);
            }
        }
        __syncthreads();

        // ---- epilogue: all 512 threads, 2 cells each (expressions frozen) ----
        {
            const int b  = tid >> 4;           // 0..31
            const int jp = tid & 15;
            const int ix = idx_lds[b];
            #pragma unroll
            for (int u = 0; u < 2; ++u){
                const int j  = (jp << 1) + u;                     // 0..31
                const int lo = ((b & 3) << 4) + (j & 15);         // owner lane
                const int vb = ((b >> 2) << 3) + (j >> 4);        // bi*8 + (j>>4)
                float g4[4];
                #pragma unroll
                for (int g = 0; g < 4; ++g){
                    const int v = vb + (g << 1);                  // + ji gate part
                    float s  = red[(      lo)*LDW + v];
                    s       += red[( 64 + lo)*LDW + v];
                    s       += red[(128 + lo)*LDW + v];
                    s       += red[(192 + lo)*LDW + v];
                    const int r = (g << 9) + j0 + j;
                    g4[g] = s + (Wih[r*Vn + ix] + bih[r] + bhh[r]);
                }
                const long bg = b0 + b;
                const int  jj = j0 + j;
                const float iv = sigf(g4[0]);
                const float fv = sigf(g4[1]);
                const float gv = tanhf(g4[2]);
                const float ov = sigf(g4[3]);
                const float cold = cws[bg*Hn + jj];
                const float cn2 = fv*cold + iv*gv;
                cws[bg*Hn + jj] = cn2;
                const float hn = ov * tanhf(cn2);
                hnext[bg*Hn + jj] = hn;
                hn_lds[b*33 + j] = hn;
            }
        }
        __syncthreads();

        // ---- partial logits (frozen) ----
        if (tid < 224){
            const float* wo = Wout + lg_v*Hn + j0;
            float s = 0.0f;
            #pragma unroll
            for (int jj = 0; jj < 32; ++jj)
                s = fmaf(hn_lds[lg_bl*33 + jj], wo[jj], s);
            atomicAdd(&lp[((long)(b0 + lg_bl)*Tn + t)*Vn + lg_v], s);
        }

        group_barrier(cnt, GBLK*(t+1));
    }

    // ---- final: hT, cT, in-place log_softmax (frozen) ----
    for (int i = gtid; i < BH; i += nthr){
        out[NLP + i]      = hbuf[i];   // T=256 even -> final h in buffer 0
        out[NLP + BH + i] = cws[i];
    }
    {
        const long row = gtid;         // exactly B*T rows
        float x[Vn]; float m = -INFINITY;
        #pragma unroll
        for (int v = 0; v < Vn; ++v){ x[v] = lp[row*Vn + v] + bout[v]; m = fmaxf(m, x[v]); }
        float s = 0.0f;
        #pragma unroll
        for (int v = 0; v < Vn; ++v) s += expf(x[v] - m);
        const float ls = logf(s);
        #pragma unroll
        for (int v = 0; v < Vn; ++v) lp[row*Vn + v] = x[v] - m - ls;
    }
}

extern "C" void kernel_launch(void* const* d_in, const int* in_sizes, int n_in,
                              void* d_out, int out_size, void* d_ws, size_t ws_size,
                              hipStream_t stream) {
    const float* h0   = (const float*)d_in[0];
    const float* c0   = (const float*)d_in[1];
    const float* tgt  = (const float*)d_in[2];
    const float* Wih  = (const float*)d_in[3];
    const float* Whh  = (const float*)d_in[4];
    const float* bih  = (const float*)d_in[5];
    const float* bhh  = (const float*)d_in[6];
    const float* Wout = (const float*)d_in[7];
    const float* bout = (const float*)d_in[8];
    float* out = (float*)d_out;
    float* ws  = (float*)d_ws;               // 3*BH floats + counters
    int*   cnts = (int*)(ws + 3*BH);

    init_kernel<<<256, 256, 0, stream>>>(out, cnts);

    void* args[] = { &h0, &c0, &tgt, &Wih, &Whh, &bih, &bhh, &Wout, &bout, &out, &ws };
    (void)hipLaunchCooperativeKernel((const void*)decoder_rnn_kernel,
                               dim3(NBLK), dim3(NTHR), args, 0, stream);
}